// Round 10
// baseline (326.376 us; speedup 1.0000x reference)
//
#include <hip/hip_runtime.h>

#define BN_   32768
#define NN    4096
#define EDGES 524288
#define DEGCAP 64

typedef __attribute__((ext_vector_type(8))) __bf16 bf16x8;
typedef __attribute__((ext_vector_type(4))) float f32x4;

// ---------------- fused prep: build_adj | conv+fc | wtrans ----------------
// blocks [0,2048): adjacency build; [2048,4096): conv; [4096,7456): weight transpose
__global__ __launch_bounds__(256)
void prep_kernel(const int* __restrict__ src, const int* __restrict__ tgt,
                 int* __restrict__ cnt, int* __restrict__ adj,
                 const float* __restrict__ x, const float* __restrict__ emb,
                 const int* __restrict__ eflag,
                 const float* __restrict__ g_w, const float* __restrict__ g_b,
                 const float* __restrict__ c_w, const float* __restrict__ c_b,
                 const float* __restrict__ fc_w, const float* __restrict__ fc_b,
                 __bf16* __restrict__ F0, __bf16* __restrict__ FF,
                 const float* __restrict__ w11, const float* __restrict__ w12,
                 const float* __restrict__ w21, const float* __restrict__ w22,
                 const float* __restrict__ w31, const float* __restrict__ w32,
                 __bf16* __restrict__ o11, __bf16* __restrict__ o12,
                 __bf16* __restrict__ o21, __bf16* __restrict__ o22,
                 __bf16* __restrict__ o31, __bf16* __restrict__ o32)
{
  const int bx = blockIdx.x;
  const int tid = threadIdx.x;

  if (bx < 2048){                       // ---- adjacency build ----
    int i = bx*256 + tid;
    int t = tgt[i];
    int pos = atomicAdd(&cnt[t], 1);
    if (pos < DEGCAP) adj[(size_t)t*DEGCAP + pos] = src[i];
    return;
  }
  if (bx >= 4096){                      // ---- weight transpose ----
    int idx = (bx - 4096)*256 + tid;
    const float* s; __bf16* d; int N, K, base;
    if (idx < 8192)        { s=w11; d=o11; K=64;  N=128;  base=0; }
    else if (idx < 24576)  { s=w12; d=o12; K=128; N=128;  base=8192; }
    else if (idx < 40960)  { s=w21; d=o21; K=128; N=128;  base=24576; }
    else if (idx < 73728)  { s=w22; d=o22; K=128; N=256;  base=40960; }
    else if (idx < 335872) { s=w31; d=o31; K=512; N=512;  base=73728; }
    else if (idx < 860160) { s=w32; d=o32; K=512; N=1024; base=335872; }
    else return;
    int t = idx - base;
    int k = t / N, n = t - k*N;
    d[(size_t)n*K + k] = (__bf16)s[t];
    return;
  }

  // ---- conv + fc ----
  __shared__ float xs[3][16];
  __shared__ float es[32][16];
  __shared__ float sel[16][64];
  const int node0 = (bx - 2048) * 16;
  const int b  = node0 >> 12;
  const int nl = node0 & 4095;
  const int e  = *eflag;

  if (tid < 48){
    int c = tid >> 4, i = tid & 15;
    xs[c][i] = x[(size_t)b*3*NN + c*NN + nl + i];
  }
  {
    int idx = tid;
#pragma unroll
    for (int p=0;p<2;p++){
      int c = idx >> 4, i = idx & 15;
      es[c][i] = emb[(size_t)b*32*NN + c*NN + nl + i];
      idx += 256;
    }
  }
  __syncthreads();
  {
    const int ch = tid & 63;
    const int g  = tid >> 6;
    float gw[3], cw[32];
#pragma unroll
    for (int c=0;c<3;c++)  gw[c] = g_w[c*64 + ch];
#pragma unroll
    for (int c=0;c<32;c++) cw[c] = c_w[c*64 + ch];
    float gb = g_b[ch], cb = c_b[ch];
#pragma unroll
    for (int q=0;q<4;q++){
      int n = g*4 + q;
      float a = gb;
#pragma unroll
      for (int c=0;c<3;c++) a += xs[c][n]*gw[c];
      float xg = fmaxf(a, 0.f);
      float s2 = cb;
#pragma unroll
      for (int c=0;c<32;c++) s2 += es[c][n]*cw[c];
      float ce = fmaxf(s2, 0.f);
      float f0 = e ? ce : xg;
      float so = e ? xg : ce;
      F0[(size_t)(node0+n)*64 + ch] = (__bf16)f0;
      sel[n][ch] = so;
    }
  }
  __syncthreads();
  {
    const int h = tid;
    float acc[16];
#pragma unroll
    for (int i=0;i<16;i++) acc[i]=0.f;
    for (int k4=0;k4<16;k4++){
      float w0 = fc_w[(k4*4+0)*256 + h];
      float w1 = fc_w[(k4*4+1)*256 + h];
      float w2 = fc_w[(k4*4+2)*256 + h];
      float w3 = fc_w[(k4*4+3)*256 + h];
#pragma unroll
      for (int i=0;i<16;i++){
        float4 sv = *(const float4*)&sel[i][k4*4];
        acc[i] += sv.x*w0 + sv.y*w1 + sv.z*w2 + sv.w*w3;
      }
    }
    float fb = fc_b[h];
#pragma unroll
    for (int i=0;i<16;i++){
      float v = fmaxf(acc[i] + fb, 0.f);
      FF[(size_t)(node0+i)*512 + 256 + h] = (__bf16)v;
    }
  }
}

// ---------------- gather-sum on single-bf16 table, padded adjacency ----------------
template<int C>
__global__ __launch_bounds__(256)
void gather_k(const __bf16* __restrict__ f, const int* __restrict__ cnt,
              const int* __restrict__ adj, __bf16* __restrict__ z)
{
  constexpr int TPN = C/8;
  const int tid  = threadIdx.x;
  int node = blockIdx.x*(256/TPN) + tid/TPN;
  if (TPN == 64) node = __builtin_amdgcn_readfirstlane(node);
  const int c8   = (tid & (TPN-1))*8;
  const int deg  = min(cnt[node], DEGCAP);
  const int* __restrict__ arow = adj + (size_t)node*DEGCAP;
  const __bf16* p = f + c8;
  float a[8];
  {
    bf16x8 sv = *(const bf16x8*)(p + (size_t)node*C);
#pragma unroll
    for (int t=0;t<8;t++) a[t] = (float)sv[t];
  }
  int j = 0;
  for (; j+8<=deg; j+=8){
    int sIdx[8];
#pragma unroll
    for (int u=0;u<8;u++) sIdx[u] = arow[j+u];
    bf16x8 v[8];
#pragma unroll
    for (int u=0;u<8;u++) v[u] = *(const bf16x8*)(p + (size_t)sIdx[u]*C);
#pragma unroll
    for (int u=0;u<8;u++)
#pragma unroll
      for (int t=0;t<8;t++) a[t] += (float)v[u][t];
  }
  for (; j+2<=deg; j+=2){
    int s0=arow[j], s1=arow[j+1];
    bf16x8 v0=*(const bf16x8*)(p+(size_t)s0*C), v1=*(const bf16x8*)(p+(size_t)s1*C);
#pragma unroll
    for (int t=0;t<8;t++) a[t] += (float)v0[t] + (float)v1[t];
  }
  if (j < deg){
    int s=arow[j];
    bf16x8 v=*(const bf16x8*)(p+(size_t)s*C);
#pragma unroll
    for (int t=0;t<8;t++) a[t] += (float)v[t];
  }
  bf16x8 o;
#pragma unroll
  for (int t=0;t<8;t++) o[t] = (__bf16)a[t];
  *(bf16x8*)(z + (size_t)node*C + c8) = o;
}

// ---------------- 128x128-tile 4-wave GEMM (layers 1-2), counted-vmcnt dbuf ----------------
template<int K, int GSWAP>
__global__ __launch_bounds__(256, 2)
void mfma_gemm(const __bf16* __restrict__ A, const __bf16* __restrict__ B,
               const float* __restrict__ bias,
               __bf16* __restrict__ outr, int ostride,
               float* __restrict__ outT, int cbase, int relu)
{
  constexpr int NK = K/32;
  __shared__ __align__(16) char smem[32768];

  const int tid = threadIdx.x;
  const int l   = tid & 63;
  const int w   = tid >> 6;
  const int wm  = w >> 1, wn = w & 1;
  const int n0  = (GSWAP ? blockIdx.y : blockIdx.x) * 128;
  const int h0  = (GSWAP ? blockIdx.x : blockIdx.y) * 128;

  f32x4 acc[4][4];
#pragma unroll
  for (int m=0;m<4;m++)
#pragma unroll
    for (int n=0;n<4;n++) acc[m][n] = (f32x4){0.f,0.f,0.f,0.f};

  const __bf16* gsrc = (w<2) ? A : B;
  const int soff = (w<2) ? 0 : 8192;
  const int rbase = (w<2) ? n0 : h0;
  const int ci0 = (w & 1) * 4;
  const int cd = (l&3) ^ ((l>>3)&3);
  const __bf16* g0 = gsrc + (size_t)(rbase + (l>>2))*K + cd*8;

  const int r16 = l & 15, q = l >> 4;
  const int fsw = ((q ^ ((r16>>1)&3)) << 4);

  auto STAGE = [&](int ks, int bb){
    char* d = smem + bb*16384 + soff;
    const __bf16* gk = g0 + ks*32;
#pragma unroll
    for (int i=0;i<4;i++){
      __builtin_amdgcn_global_load_lds(
        (const __attribute__((address_space(1))) void*)(gk + (size_t)(ci0+i)*16*K),
        (__attribute__((address_space(3))) void*)(d + (ci0+i)*1024), 16, 0, 0);
    }
  };

  STAGE(0, 0);
  STAGE(1, 1);

  for (int ks=0; ks<NK; ks++){
    const int bb = ks & 1;
    if (ks < NK-1) asm volatile("s_waitcnt vmcnt(4)" ::: "memory");
    else           asm volatile("s_waitcnt vmcnt(0)" ::: "memory");
    asm volatile("s_barrier" ::: "memory");

    const char* base = smem + bb*16384;
    bf16x8 fa[4], fb[4];
#pragma unroll
    for (int m=0;m<4;m++)
      fa[m] = *(const bf16x8*)(base + (wm*64 + m*16 + r16)*64 + fsw);
#pragma unroll
    for (int n=0;n<4;n++)
      fb[n] = *(const bf16x8*)(base + 8192 + (wn*64 + n*16 + r16)*64 + fsw);
    asm volatile("s_waitcnt lgkmcnt(0)" ::: "memory");
    __builtin_amdgcn_sched_barrier(0);

    __builtin_amdgcn_s_setprio(1);
#pragma unroll
    for (int m=0;m<4;m++)
#pragma unroll
      for (int n=0;n<4;n++)
        acc[m][n] = __builtin_amdgcn_mfma_f32_16x16x32_bf16(fa[m], fb[n], acc[m][n], 0,0,0);
    __builtin_amdgcn_s_setprio(0);

    asm volatile("s_barrier" ::: "memory");
    if (ks+2 < NK) STAGE(ks+2, bb);
  }

  __syncthreads();
  float* scratch = (float*)(void*)smem + w*1088;

  float bv[4];
#pragma unroll
  for (int n=0;n<4;n++) bv[n] = bias[h0 + wn*64 + n*16 + r16];

#pragma unroll
  for (int m=0;m<4;m++){
#pragma unroll
    for (int n=0;n<4;n++)
#pragma unroll
      for (int r=0;r<4;r++){
        float v = acc[m][n][r] + bv[n];
        if (relu) v = fmaxf(v, 0.f);
        scratch[(q*4+r)*68 + n*16 + r16] = v;
      }
    if (outr){
      const int row = l>>2, ch = (l&3)*16;
      bf16x8 H0,H1;
#pragma unroll
      for (int t=0;t<16;t++){
        float xv = scratch[row*68 + ch + t];
        if (t<8) H0[t]=(__bf16)xv; else H1[t-8]=(__bf16)xv;
      }
      size_t o = (size_t)(n0 + wm*64 + m*16 + row)*ostride + h0 + wn*64 + ch;
      *(bf16x8*)(outr+o)   = H0;
      *(bf16x8*)(outr+o+8) = H1;
    }
    if (outT){
      const int b = n0 >> 12, nl = n0 & 4095;
      const int rr0 = (l&3)*4;
#pragma unroll
      for (int j=0;j<4;j++){
        const int c = (l>>2) + 16*j;
        f32x4 v;
#pragma unroll
        for (int i=0;i<4;i++) v[i] = scratch[(rr0+i)*68 + c];
        size_t o = ((size_t)b*1408 + cbase + h0 + wn*64 + c)*NN + nl + wm*64 + m*16 + rr0;
        *(f32x4*)(outT + o) = v;
      }
    }
  }
}

// ---------------- 256x128-tile 8-wave GEMM (layer 3), counted-vmcnt dbuf ----------------
// A: [M][K], tile 256 rows; B: [NH][K], tile 128 cols. 8 waves = 4(m) x 2(n), each 64x64.
// Staging per K-step: A 16KB (waves 0-3, 4 loads/lane), B 8KB (waves 4-7, 2 loads/lane).
// LDS: 2 x (A 16KB | B 8KB) = 48KB. Epilogue scratch 8x1088 f32 = 34KB (reuse).
template<int K, int GSWAP>
__global__ __launch_bounds__(512, 2)
void mfma_gemm256(const __bf16* __restrict__ A, const __bf16* __restrict__ B,
                  const float* __restrict__ bias,
                  __bf16* __restrict__ outr, int ostride,
                  float* __restrict__ outT, int cbase, int relu)
{
  constexpr int NK = K/32;
  __shared__ __align__(16) char smem[49152];

  const int tid = threadIdx.x;
  const int l   = tid & 63;
  const int w   = tid >> 6;          // 0..7
  const int wm  = w >> 1, wn = w & 1;
  const int n0  = (GSWAP ? blockIdx.y : blockIdx.x) * 256;
  const int h0  = (GSWAP ? blockIdx.x : blockIdx.y) * 128;

  f32x4 acc[4][4];
#pragma unroll
  for (int m=0;m<4;m++)
#pragma unroll
    for (int n=0;n<4;n++) acc[m][n] = (f32x4){0.f,0.f,0.f,0.f};

  const bool isA = (w < 4);
  const __bf16* gsrc = isA ? A : B;
  const int rbase = isA ? (n0 + w*64) : (h0 + (w-4)*32);
  const int soff  = isA ? (w*4096) : (16384 + (w-4)*2048);
  const int cd = (l&3) ^ ((l>>3)&3);
  const __bf16* g0 = gsrc + (size_t)(rbase + (l>>2))*K + cd*8;

  const int r16 = l & 15, q = l >> 4;
  const int fsw = ((q ^ ((r16>>1)&3)) << 4);

  auto STAGE = [&](int ks, int bb){
    char* d = smem + bb*24576 + soff;
    const __bf16* gk = g0 + ks*32;
    if (isA){
#pragma unroll
      for (int i=0;i<4;i++){
        __builtin_amdgcn_global_load_lds(
          (const __attribute__((address_space(1))) void*)(gk + (size_t)i*16*K),
          (__attribute__((address_space(3))) void*)(d + i*1024), 16, 0, 0);
      }
    } else {
#pragma unroll
      for (int i=0;i<2;i++){
        __builtin_amdgcn_global_load_lds(
          (const __attribute__((address_space(1))) void*)(gk + (size_t)i*16*K),
          (__attribute__((address_space(3))) void*)(d + i*1024), 16, 0, 0);
      }
    }
  };

  STAGE(0, 0);
  STAGE(1, 1);

  for (int ks=0; ks<NK; ks++){
    const int bb = ks & 1;
    if (ks < NK-1){
      if (isA) asm volatile("s_waitcnt vmcnt(4)" ::: "memory");
      else     asm volatile("s_waitcnt vmcnt(2)" ::: "memory");
    } else {
      asm volatile("s_waitcnt vmcnt(0)" ::: "memory");
    }
    asm volatile("s_barrier" ::: "memory");

    const char* base = smem + bb*24576;
    bf16x8 fa[4], fb[4];
#pragma unroll
    for (int m=0;m<4;m++)
      fa[m] = *(const bf16x8*)(base + (wm*64 + m*16 + r16)*64 + fsw);
#pragma unroll
    for (int n=0;n<4;n++)
      fb[n] = *(const bf16x8*)(base + 16384 + (wn*64 + n*16 + r16)*64 + fsw);
    asm volatile("s_waitcnt lgkmcnt(0)" ::: "memory");
    __builtin_amdgcn_sched_barrier(0);

    __builtin_amdgcn_s_setprio(1);
#pragma unroll
    for (int m=0;m<4;m++)
#pragma unroll
      for (int n=0;n<4;n++)
        acc[m][n] = __builtin_amdgcn_mfma_f32_16x16x32_bf16(fa[m], fb[n], acc[m][n], 0,0,0);
    __builtin_amdgcn_s_setprio(0);

    asm volatile("s_barrier" ::: "memory");
    if (ks+2 < NK) STAGE(ks+2, bb);
  }

  __syncthreads();
  float* scratch = (float*)(void*)smem + w*1088;

  float bv[4];
#pragma unroll
  for (int n=0;n<4;n++) bv[n] = bias[h0 + wn*64 + n*16 + r16];

#pragma unroll
  for (int m=0;m<4;m++){
#pragma unroll
    for (int n=0;n<4;n++)
#pragma unroll
      for (int r=0;r<4;r++){
        float v = acc[m][n][r] + bv[n];
        if (relu) v = fmaxf(v, 0.f);
        scratch[(q*4+r)*68 + n*16 + r16] = v;
      }
    if (outr){
      const int row = l>>2, ch = (l&3)*16;
      bf16x8 H0,H1;
#pragma unroll
      for (int t=0;t<16;t++){
        float xv = scratch[row*68 + ch + t];
        if (t<8) H0[t]=(__bf16)xv; else H1[t-8]=(__bf16)xv;
      }
      size_t o = (size_t)(n0 + wm*64 + m*16 + row)*ostride + h0 + wn*64 + ch;
      *(bf16x8*)(outr+o)   = H0;
      *(bf16x8*)(outr+o+8) = H1;
    }
    if (outT){
      const int b = n0 >> 12, nl = n0 & 4095;
      const int rr0 = (l&3)*4;
#pragma unroll
      for (int j=0;j<4;j++){
        const int c = (l>>2) + 16*j;
        f32x4 v;
#pragma unroll
        for (int i=0;i<4;i++) v[i] = scratch[(rr0+i)*68 + c];
        size_t o = ((size_t)b*1408 + cbase + h0 + wn*64 + c)*NN + nl + wm*64 + m*16 + rr0;
        *(f32x4*)(outT + o) = v;
      }
    }
  }
}

extern "C" void kernel_launch(void* const* d_in, const int* in_sizes, int n_in,
                              void* d_out, int out_size, void* d_ws, size_t ws_size,
                              hipStream_t stream)
{
  const float* x     = (const float*)d_in[0];
  const float* emb   = (const float*)d_in[1];
  const int*   ei    = (const int*)d_in[2];
  const int*   eflag = (const int*)d_in[3];
  const float* g_w   = (const float*)d_in[4];
  const float* g_b   = (const float*)d_in[5];
  const float* c_w   = (const float*)d_in[6];
  const float* c_b   = (const float*)d_in[7];
  const float* m1w1  = (const float*)d_in[8];
  const float* m1b1  = (const float*)d_in[9];
  const float* m1w2  = (const float*)d_in[10];
  const float* m1b2  = (const float*)d_in[11];
  const float* m2w1  = (const float*)d_in[12];
  const float* m2b1  = (const float*)d_in[13];
  const float* m2w2  = (const float*)d_in[14];
  const float* m2b2  = (const float*)d_in[15];
  const float* m3w1  = (const float*)d_in[16];
  const float* m3b1  = (const float*)d_in[17];
  const float* m3w2  = (const float*)d_in[18];
  const float* m3b2  = (const float*)d_in[19];
  const float* fc_w  = (const float*)d_in[20];
  const float* fc_b  = (const float*)d_in[21];
  float* out = (float*)d_out;
  char*  ws  = (char*)d_ws;

  // ---- workspace layout (audited, disjoint) ----
  __bf16* F0 = (__bf16*)(ws + 0);            // [  0,   4 MB)  [BN][64]
  __bf16* Z1 = (__bf16*)(ws + 4194304);      // [  4,   8 MB)
  __bf16* H1 = (__bf16*)(ws + 8388608);      // [  8,  16 MB)  [BN][128]
  __bf16* F1 = (__bf16*)(ws + 16777216);     // [ 16,  24 MB)
  __bf16* Z2 = (__bf16*)(ws + 25165824);     // [ 24,  32 MB)
  __bf16* H2 = (__bf16*)(ws + 33554432);     // [ 32,  40 MB)
  __bf16* FF = (__bf16*)(ws + 41943040);     // [ 40,  72 MB)  [BN][512]
  __bf16* Z3 = (__bf16*)(ws + 75497472);     // [ 72, 104 MB)
  __bf16* H3 = (__bf16*)(ws + 109051904);    // [104, 136 MB)  ends 142606336
  // Weights (single bf16, transposed [N][K]) — at 144 MB
  char* wb = ws + 150994944;
  __bf16* W11=(__bf16*)(wb+0);
  __bf16* W12=(__bf16*)(wb+16384);
  __bf16* W21=(__bf16*)(wb+49152);
  __bf16* W22=(__bf16*)(wb+81920);
  __bf16* W31=(__bf16*)(wb+147456);
  __bf16* W32=(__bf16*)(wb+671744);          // ends wb+1720320
  // adjacency
  int* adj = (int*)(ws + 153092096);         // 8 MB [BN][64]
  int* cnt = (int*)(ws + 161480704);         // 128 KB

  const int* srcp = ei;
  const int* tgtp = ei + EDGES;

  hipMemsetAsync(cnt, 0, BN_*4, stream);
  prep_kernel<<<7456, 256, 0, stream>>>(srcp, tgtp, cnt, adj,
      x, emb, eflag, g_w, g_b, c_w, c_b, fc_w, fc_b, F0, FF,
      m1w1, m1w2, m2w1, m2w2, m3w1, m3w2, W11, W12, W21, W22, W31, W32);

  // ---- GIN layer 1: 64 -> 128 -> 128 ----
  gather_k<64><<<BN_/32, 256, 0, stream>>>(F0, cnt, adj, Z1);
  mfma_gemm<64,0><<<dim3(BN_/128, 1), 256, 0, stream>>>(
      Z1, W11, m1b1, H1, 128, nullptr, 0, 1);
  mfma_gemm<128,0><<<dim3(BN_/128, 1), 256, 0, stream>>>(
      H1, W12, m1b2, F1, 128, out, 0, 1);

  // ---- GIN layer 2: 128 -> 128 -> 256 ----
  gather_k<128><<<BN_/16, 256, 0, stream>>>(F1, cnt, adj, Z2);
  mfma_gemm<128,0><<<dim3(BN_/128, 1), 256, 0, stream>>>(
      Z2, W21, m2b1, H2, 128, nullptr, 0, 1);
  mfma_gemm<128,0><<<dim3(BN_/128, 2), 256, 0, stream>>>(
      H2, W22, m2b2, FF, 512, out, 128, 1);

  // ---- GIN layer 3: 512 -> 512 -> 1024 (256x128 8-wave tiles) ----
  gather_k<512><<<BN_/4, 256, 0, stream>>>(FF, cnt, adj, Z3);
  mfma_gemm256<512,1><<<dim3(4, BN_/256), 512, 0, stream>>>(
      Z3, W31, m3b1, H3, 512, nullptr, 0, 1);
  mfma_gemm256<512,1><<<dim3(8, BN_/256), 512, 0, stream>>>(
      H3, W32, m3b2, nullptr, 0, out, 384, 0);
}

// Round 11
// 309.615 us; speedup vs baseline: 1.0541x; 1.0541x over previous
//
#include <hip/hip_runtime.h>

#define BN_   32768
#define NN    4096
#define EDGES 524288
#define DEGCAP 64

typedef __attribute__((ext_vector_type(8))) __bf16 bf16x8;
typedef __attribute__((ext_vector_type(4))) float f32x4;

// ---------------- fused prep: build_adj | conv+fc | wtrans ----------------
// blocks [0,2048): adjacency build; [2048,4096): conv; [4096,7456): weight transpose
__global__ __launch_bounds__(256)
void prep_kernel(const int* __restrict__ src, const int* __restrict__ tgt,
                 int* __restrict__ cnt, int* __restrict__ adj,
                 const float* __restrict__ x, const float* __restrict__ emb,
                 const int* __restrict__ eflag,
                 const float* __restrict__ g_w, const float* __restrict__ g_b,
                 const float* __restrict__ c_w, const float* __restrict__ c_b,
                 const float* __restrict__ fc_w, const float* __restrict__ fc_b,
                 __bf16* __restrict__ F0, __bf16* __restrict__ FF,
                 const float* __restrict__ w11, const float* __restrict__ w12,
                 const float* __restrict__ w21, const float* __restrict__ w22,
                 const float* __restrict__ w31, const float* __restrict__ w32,
                 __bf16* __restrict__ o11, __bf16* __restrict__ o12,
                 __bf16* __restrict__ o21, __bf16* __restrict__ o22,
                 __bf16* __restrict__ o31, __bf16* __restrict__ o32)
{
  const int bx = blockIdx.x;
  const int tid = threadIdx.x;

  if (bx < 2048){                       // ---- adjacency build ----
    int i = bx*256 + tid;
    int t = tgt[i];
    int pos = atomicAdd(&cnt[t], 1);
    if (pos < DEGCAP) adj[(size_t)t*DEGCAP + pos] = src[i];
    return;
  }
  if (bx >= 4096){                      // ---- weight transpose ----
    int idx = (bx - 4096)*256 + tid;
    const float* s; __bf16* d; int N, K, base;
    if (idx < 8192)        { s=w11; d=o11; K=64;  N=128;  base=0; }
    else if (idx < 24576)  { s=w12; d=o12; K=128; N=128;  base=8192; }
    else if (idx < 40960)  { s=w21; d=o21; K=128; N=128;  base=24576; }
    else if (idx < 73728)  { s=w22; d=o22; K=128; N=256;  base=40960; }
    else if (idx < 335872) { s=w31; d=o31; K=512; N=512;  base=73728; }
    else if (idx < 860160) { s=w32; d=o32; K=512; N=1024; base=335872; }
    else return;
    int t = idx - base;
    int k = t / N, n = t - k*N;
    d[(size_t)n*K + k] = (__bf16)s[t];
    return;
  }

  // ---- conv + fc ----
  __shared__ float xs[3][16];
  __shared__ float es[32][16];
  __shared__ float sel[16][64];
  const int node0 = (bx - 2048) * 16;
  const int b  = node0 >> 12;
  const int nl = node0 & 4095;
  const int e  = *eflag;

  if (tid < 48){
    int c = tid >> 4, i = tid & 15;
    xs[c][i] = x[(size_t)b*3*NN + c*NN + nl + i];
  }
  {
    int idx = tid;
#pragma unroll
    for (int p=0;p<2;p++){
      int c = idx >> 4, i = idx & 15;
      es[c][i] = emb[(size_t)b*32*NN + c*NN + nl + i];
      idx += 256;
    }
  }
  __syncthreads();
  {
    const int ch = tid & 63;
    const int g  = tid >> 6;
    float gw[3], cw[32];
#pragma unroll
    for (int c=0;c<3;c++)  gw[c] = g_w[c*64 + ch];
#pragma unroll
    for (int c=0;c<32;c++) cw[c] = c_w[c*64 + ch];
    float gb = g_b[ch], cb = c_b[ch];
#pragma unroll
    for (int q=0;q<4;q++){
      int n = g*4 + q;
      float a = gb;
#pragma unroll
      for (int c=0;c<3;c++) a += xs[c][n]*gw[c];
      float xg = fmaxf(a, 0.f);
      float s2 = cb;
#pragma unroll
      for (int c=0;c<32;c++) s2 += es[c][n]*cw[c];
      float ce = fmaxf(s2, 0.f);
      float f0 = e ? ce : xg;
      float so = e ? xg : ce;
      F0[(size_t)(node0+n)*64 + ch] = (__bf16)f0;
      sel[n][ch] = so;
    }
  }
  __syncthreads();
  {
    const int h = tid;
    float acc[16];
#pragma unroll
    for (int i=0;i<16;i++) acc[i]=0.f;
    for (int k4=0;k4<16;k4++){
      float w0 = fc_w[(k4*4+0)*256 + h];
      float w1 = fc_w[(k4*4+1)*256 + h];
      float w2 = fc_w[(k4*4+2)*256 + h];
      float w3 = fc_w[(k4*4+3)*256 + h];
#pragma unroll
      for (int i=0;i<16;i++){
        float4 sv = *(const float4*)&sel[i][k4*4];
        acc[i] += sv.x*w0 + sv.y*w1 + sv.z*w2 + sv.w*w3;
      }
    }
    float fb = fc_b[h];
#pragma unroll
    for (int i=0;i<16;i++){
      float v = fmaxf(acc[i] + fb, 0.f);
      FF[(size_t)(node0+i)*512 + 256 + h] = (__bf16)v;
    }
  }
}

// ---------------- gather-sum on single-bf16 table, padded adjacency ----------------
template<int C>
__global__ __launch_bounds__(256)
void gather_k(const __bf16* __restrict__ f, const int* __restrict__ cnt,
              const int* __restrict__ adj, __bf16* __restrict__ z)
{
  constexpr int TPN = C/8;
  const int tid  = threadIdx.x;
  int node = blockIdx.x*(256/TPN) + tid/TPN;
  if (TPN == 64) node = __builtin_amdgcn_readfirstlane(node);
  const int c8   = (tid & (TPN-1))*8;
  const int deg  = min(cnt[node], DEGCAP);
  const int* __restrict__ arow = adj + (size_t)node*DEGCAP;
  const __bf16* p = f + c8;
  float a[8];
  {
    bf16x8 sv = *(const bf16x8*)(p + (size_t)node*C);
#pragma unroll
    for (int t=0;t<8;t++) a[t] = (float)sv[t];
  }
  int j = 0;
  for (; j+8<=deg; j+=8){
    int sIdx[8];
#pragma unroll
    for (int u=0;u<8;u++) sIdx[u] = arow[j+u];
    bf16x8 v[8];
#pragma unroll
    for (int u=0;u<8;u++) v[u] = *(const bf16x8*)(p + (size_t)sIdx[u]*C);
#pragma unroll
    for (int u=0;u<8;u++)
#pragma unroll
      for (int t=0;t<8;t++) a[t] += (float)v[u][t];
  }
  for (; j+2<=deg; j+=2){
    int s0=arow[j], s1=arow[j+1];
    bf16x8 v0=*(const bf16x8*)(p+(size_t)s0*C), v1=*(const bf16x8*)(p+(size_t)s1*C);
#pragma unroll
    for (int t=0;t<8;t++) a[t] += (float)v0[t] + (float)v1[t];
  }
  if (j < deg){
    int s=arow[j];
    bf16x8 v=*(const bf16x8*)(p+(size_t)s*C);
#pragma unroll
    for (int t=0;t<8;t++) a[t] += (float)v[t];
  }
  bf16x8 o;
#pragma unroll
  for (int t=0;t<8;t++) o[t] = (__bf16)a[t];
  *(bf16x8*)(z + (size_t)node*C + c8) = o;
}

// ---------------- 128x128-tile 4-wave GEMM, counted-vmcnt dbuf (round-9 proven) ----------------
template<int K, int GSWAP>
__global__ __launch_bounds__(256, 2)
void mfma_gemm(const __bf16* __restrict__ A, const __bf16* __restrict__ B,
               const float* __restrict__ bias,
               __bf16* __restrict__ outr, int ostride,
               float* __restrict__ outT, int cbase, int relu)
{
  constexpr int NK = K/32;
  __shared__ __align__(16) char smem[32768];

  const int tid = threadIdx.x;
  const int l   = tid & 63;
  const int w   = tid >> 6;
  const int wm  = w >> 1, wn = w & 1;
  const int n0  = (GSWAP ? blockIdx.y : blockIdx.x) * 128;
  const int h0  = (GSWAP ? blockIdx.x : blockIdx.y) * 128;

  f32x4 acc[4][4];
#pragma unroll
  for (int m=0;m<4;m++)
#pragma unroll
    for (int n=0;n<4;n++) acc[m][n] = (f32x4){0.f,0.f,0.f,0.f};

  const __bf16* gsrc = (w<2) ? A : B;
  const int soff = (w<2) ? 0 : 8192;
  const int rbase = (w<2) ? n0 : h0;
  const int ci0 = (w & 1) * 4;
  const int cd = (l&3) ^ ((l>>3)&3);
  const __bf16* g0 = gsrc + (size_t)(rbase + (l>>2))*K + cd*8;

  const int r16 = l & 15, q = l >> 4;
  const int fsw = ((q ^ ((r16>>1)&3)) << 4);

  auto STAGE = [&](int ks, int bb){
    char* d = smem + bb*16384 + soff;
    const __bf16* gk = g0 + ks*32;
#pragma unroll
    for (int i=0;i<4;i++){
      __builtin_amdgcn_global_load_lds(
        (const __attribute__((address_space(1))) void*)(gk + (size_t)(ci0+i)*16*K),
        (__attribute__((address_space(3))) void*)(d + (ci0+i)*1024), 16, 0, 0);
    }
  };

  STAGE(0, 0);
  STAGE(1, 1);

  for (int ks=0; ks<NK; ks++){
    const int bb = ks & 1;
    if (ks < NK-1) asm volatile("s_waitcnt vmcnt(4)" ::: "memory");
    else           asm volatile("s_waitcnt vmcnt(0)" ::: "memory");
    asm volatile("s_barrier" ::: "memory");

    const char* base = smem + bb*16384;
    bf16x8 fa[4], fb[4];
#pragma unroll
    for (int m=0;m<4;m++)
      fa[m] = *(const bf16x8*)(base + (wm*64 + m*16 + r16)*64 + fsw);
#pragma unroll
    for (int n=0;n<4;n++)
      fb[n] = *(const bf16x8*)(base + 8192 + (wn*64 + n*16 + r16)*64 + fsw);
    asm volatile("s_waitcnt lgkmcnt(0)" ::: "memory");
    __builtin_amdgcn_sched_barrier(0);

    __builtin_amdgcn_s_setprio(1);
#pragma unroll
    for (int m=0;m<4;m++)
#pragma unroll
      for (int n=0;n<4;n++)
        acc[m][n] = __builtin_amdgcn_mfma_f32_16x16x32_bf16(fa[m], fb[n], acc[m][n], 0,0,0);
    __builtin_amdgcn_s_setprio(0);

    asm volatile("s_barrier" ::: "memory");
    if (ks+2 < NK) STAGE(ks+2, bb);
  }

  __syncthreads();
  float* scratch = (float*)(void*)smem + w*1088;

  float bv[4];
#pragma unroll
  for (int n=0;n<4;n++) bv[n] = bias[h0 + wn*64 + n*16 + r16];

#pragma unroll
  for (int m=0;m<4;m++){
#pragma unroll
    for (int n=0;n<4;n++)
#pragma unroll
      for (int r=0;r<4;r++){
        float v = acc[m][n][r] + bv[n];
        if (relu) v = fmaxf(v, 0.f);
        scratch[(q*4+r)*68 + n*16 + r16] = v;
      }
    if (outr){
      const int row = l>>2, ch = (l&3)*16;
      bf16x8 H0,H1;
#pragma unroll
      for (int t=0;t<16;t++){
        float xv = scratch[row*68 + ch + t];
        if (t<8) H0[t]=(__bf16)xv; else H1[t-8]=(__bf16)xv;
      }
      size_t o = (size_t)(n0 + wm*64 + m*16 + row)*ostride + h0 + wn*64 + ch;
      *(bf16x8*)(outr+o)   = H0;
      *(bf16x8*)(outr+o+8) = H1;
    }
    if (outT){
      const int b = n0 >> 12, nl = n0 & 4095;
      const int rr0 = (l&3)*4;
#pragma unroll
      for (int j=0;j<4;j++){
        const int c = (l>>2) + 16*j;
        f32x4 v;
#pragma unroll
        for (int i=0;i<4;i++) v[i] = scratch[(rr0+i)*68 + c];
        size_t o = ((size_t)b*1408 + cbase + h0 + wn*64 + c)*NN + nl + wm*64 + m*16 + rr0;
        *(f32x4*)(outT + o) = v;
      }
    }
  }
}

extern "C" void kernel_launch(void* const* d_in, const int* in_sizes, int n_in,
                              void* d_out, int out_size, void* d_ws, size_t ws_size,
                              hipStream_t stream)
{
  const float* x     = (const float*)d_in[0];
  const float* emb   = (const float*)d_in[1];
  const int*   ei    = (const int*)d_in[2];
  const int*   eflag = (const int*)d_in[3];
  const float* g_w   = (const float*)d_in[4];
  const float* g_b   = (const float*)d_in[5];
  const float* c_w   = (const float*)d_in[6];
  const float* c_b   = (const float*)d_in[7];
  const float* m1w1  = (const float*)d_in[8];
  const float* m1b1  = (const float*)d_in[9];
  const float* m1w2  = (const float*)d_in[10];
  const float* m1b2  = (const float*)d_in[11];
  const float* m2w1  = (const float*)d_in[12];
  const float* m2b1  = (const float*)d_in[13];
  const float* m2w2  = (const float*)d_in[14];
  const float* m2b2  = (const float*)d_in[15];
  const float* m3w1  = (const float*)d_in[16];
  const float* m3b1  = (const float*)d_in[17];
  const float* m3w2  = (const float*)d_in[18];
  const float* m3b2  = (const float*)d_in[19];
  const float* fc_w  = (const float*)d_in[20];
  const float* fc_b  = (const float*)d_in[21];
  float* out = (float*)d_out;
  char*  ws  = (char*)d_ws;

  // ---- workspace layout (audited, disjoint) ----
  __bf16* F0 = (__bf16*)(ws + 0);            // [  0,   4 MB)  [BN][64]
  __bf16* Z1 = (__bf16*)(ws + 4194304);      // [  4,   8 MB)
  __bf16* H1 = (__bf16*)(ws + 8388608);      // [  8,  16 MB)  [BN][128]
  __bf16* F1 = (__bf16*)(ws + 16777216);     // [ 16,  24 MB)
  __bf16* Z2 = (__bf16*)(ws + 25165824);     // [ 24,  32 MB)
  __bf16* H2 = (__bf16*)(ws + 33554432);     // [ 32,  40 MB)
  __bf16* FF = (__bf16*)(ws + 41943040);     // [ 40,  72 MB)  [BN][512]
  __bf16* Z3 = (__bf16*)(ws + 75497472);     // [ 72, 104 MB)
  __bf16* H3 = (__bf16*)(ws + 109051904);    // [104, 136 MB)  ends 142606336
  // Weights (single bf16, transposed [N][K]) — at 144 MB
  char* wb = ws + 150994944;
  __bf16* W11=(__bf16*)(wb+0);
  __bf16* W12=(__bf16*)(wb+16384);
  __bf16* W21=(__bf16*)(wb+49152);
  __bf16* W22=(__bf16*)(wb+81920);
  __bf16* W31=(__bf16*)(wb+147456);
  __bf16* W32=(__bf16*)(wb+671744);          // ends wb+1720320
  // adjacency
  int* adj = (int*)(ws + 153092096);         // 8 MB [BN][64]
  int* cnt = (int*)(ws + 161480704);         // 128 KB

  const int* srcp = ei;
  const int* tgtp = ei + EDGES;

  hipMemsetAsync(cnt, 0, BN_*4, stream);
  prep_kernel<<<7456, 256, 0, stream>>>(srcp, tgtp, cnt, adj,
      x, emb, eflag, g_w, g_b, c_w, c_b, fc_w, fc_b, F0, FF,
      m1w1, m1w2, m2w1, m2w2, m3w1, m3w2, W11, W12, W21, W22, W31, W32);

  // ---- GIN layer 1: 64 -> 128 -> 128 ----
  gather_k<64><<<BN_/32, 256, 0, stream>>>(F0, cnt, adj, Z1);
  mfma_gemm<64,0><<<dim3(BN_/128, 1), 256, 0, stream>>>(
      Z1, W11, m1b1, H1, 128, nullptr, 0, 1);
  mfma_gemm<128,0><<<dim3(BN_/128, 1), 256, 0, stream>>>(
      H1, W12, m1b2, F1, 128, out, 0, 1);

  // ---- GIN layer 2: 128 -> 128 -> 256 ----
  gather_k<128><<<BN_/16, 256, 0, stream>>>(F1, cnt, adj, Z2);
  mfma_gemm<128,0><<<dim3(BN_/128, 1), 256, 0, stream>>>(
      Z2, W21, m2b1, H2, 128, nullptr, 0, 1);
  mfma_gemm<128,0><<<dim3(BN_/128, 2), 256, 0, stream>>>(
      H2, W22, m2b2, FF, 512, out, 128, 1);

  // ---- GIN layer 3: 512 -> 512 -> 1024 (128x128 4-wave tiles, round-9 proven) ----
  gather_k<512><<<BN_/4, 256, 0, stream>>>(FF, cnt, adj, Z3);
  mfma_gemm<512,1><<<dim3(4, BN_/128), 256, 0, stream>>>(
      Z3, W31, m3b1, H3, 512, nullptr, 0, 1);
  mfma_gemm<512,1><<<dim3(8, BN_/128), 256, 0, stream>>>(
      H3, W32, m3b2, nullptr, 0, out, 384, 0);
}

// Round 12
// 299.428 us; speedup vs baseline: 1.0900x; 1.0340x over previous
//
#include <hip/hip_runtime.h>

#define BN_   32768
#define NN    4096
#define EDGES 524288
#define DEGCAP 64

typedef __attribute__((ext_vector_type(8))) __bf16 bf16x8;
typedef __attribute__((ext_vector_type(4))) float f32x4;

// ---------------- fused prep: build_adj | conv+fc | wtrans ----------------
__global__ __launch_bounds__(256)
void prep_kernel(const int* __restrict__ src, const int* __restrict__ tgt,
                 int* __restrict__ cnt, int* __restrict__ adj,
                 const float* __restrict__ x, const float* __restrict__ emb,
                 const int* __restrict__ eflag,
                 const float* __restrict__ g_w, const float* __restrict__ g_b,
                 const float* __restrict__ c_w, const float* __restrict__ c_b,
                 const float* __restrict__ fc_w, const float* __restrict__ fc_b,
                 __bf16* __restrict__ F0, __bf16* __restrict__ FF,
                 const float* __restrict__ w11, const float* __restrict__ w12,
                 const float* __restrict__ w21, const float* __restrict__ w22,
                 const float* __restrict__ w31, const float* __restrict__ w32,
                 __bf16* __restrict__ o11, __bf16* __restrict__ o12,
                 __bf16* __restrict__ o21, __bf16* __restrict__ o22,
                 __bf16* __restrict__ o31, __bf16* __restrict__ o32)
{
  const int bx = blockIdx.x;
  const int tid = threadIdx.x;

  if (bx < 2048){                       // ---- adjacency build ----
    int i = bx*256 + tid;
    int t = tgt[i];
    int pos = atomicAdd(&cnt[t], 1);
    if (pos < DEGCAP) adj[(size_t)t*DEGCAP + pos] = src[i];
    return;
  }
  if (bx >= 4096){                      // ---- weight transpose ----
    int idx = (bx - 4096)*256 + tid;
    const float* s; __bf16* d; int N, K, base;
    if (idx < 8192)        { s=w11; d=o11; K=64;  N=128;  base=0; }
    else if (idx < 24576)  { s=w12; d=o12; K=128; N=128;  base=8192; }
    else if (idx < 40960)  { s=w21; d=o21; K=128; N=128;  base=24576; }
    else if (idx < 73728)  { s=w22; d=o22; K=128; N=256;  base=40960; }
    else if (idx < 335872) { s=w31; d=o31; K=512; N=512;  base=73728; }
    else if (idx < 860160) { s=w32; d=o32; K=512; N=1024; base=335872; }
    else return;
    int t = idx - base;
    int k = t / N, n = t - k*N;
    d[(size_t)n*K + k] = (__bf16)s[t];
    return;
  }

  // ---- conv + fc ----
  __shared__ float xs[3][16];
  __shared__ float es[32][16];
  __shared__ float sel[16][64];
  const int node0 = (bx - 2048) * 16;
  const int b  = node0 >> 12;
  const int nl = node0 & 4095;
  const int e  = *eflag;

  if (tid < 48){
    int c = tid >> 4, i = tid & 15;
    xs[c][i] = x[(size_t)b*3*NN + c*NN + nl + i];
  }
  {
    int idx = tid;
#pragma unroll
    for (int p=0;p<2;p++){
      int c = idx >> 4, i = idx & 15;
      es[c][i] = emb[(size_t)b*32*NN + c*NN + nl + i];
      idx += 256;
    }
  }
  __syncthreads();
  {
    const int ch = tid & 63;
    const int g  = tid >> 6;
    float gw[3], cw[32];
#pragma unroll
    for (int c=0;c<3;c++)  gw[c] = g_w[c*64 + ch];
#pragma unroll
    for (int c=0;c<32;c++) cw[c] = c_w[c*64 + ch];
    float gb = g_b[ch], cb = c_b[ch];
#pragma unroll
    for (int q=0;q<4;q++){
      int n = g*4 + q;
      float a = gb;
#pragma unroll
      for (int c=0;c<3;c++) a += xs[c][n]*gw[c];
      float xg = fmaxf(a, 0.f);
      float s2 = cb;
#pragma unroll
      for (int c=0;c<32;c++) s2 += es[c][n]*cw[c];
      float ce = fmaxf(s2, 0.f);
      float f0 = e ? ce : xg;
      float so = e ? xg : ce;
      F0[(size_t)(node0+n)*64 + ch] = (__bf16)f0;
      sel[n][ch] = so;
    }
  }
  __syncthreads();
  {
    const int h = tid;
    float acc[16];
#pragma unroll
    for (int i=0;i<16;i++) acc[i]=0.f;
    for (int k4=0;k4<16;k4++){
      float w0 = fc_w[(k4*4+0)*256 + h];
      float w1 = fc_w[(k4*4+1)*256 + h];
      float w2 = fc_w[(k4*4+2)*256 + h];
      float w3 = fc_w[(k4*4+3)*256 + h];
#pragma unroll
      for (int i=0;i<16;i++){
        float4 sv = *(const float4*)&sel[i][k4*4];
        acc[i] += sv.x*w0 + sv.y*w1 + sv.z*w2 + sv.w*w3;
      }
    }
    float fb = fc_b[h];
#pragma unroll
    for (int i=0;i<16;i++){
      float v = fmaxf(acc[i] + fb, 0.f);
      FF[(size_t)(node0+i)*512 + 256 + h] = (__bf16)v;
    }
  }
}

// ---------------- gather-sum on single-bf16 table, padded adjacency ----------------
template<int C>
__global__ __launch_bounds__(256)
void gather_k(const __bf16* __restrict__ f, const int* __restrict__ cnt,
              const int* __restrict__ adj, __bf16* __restrict__ z)
{
  constexpr int TPN = C/8;
  const int tid  = threadIdx.x;
  int node = blockIdx.x*(256/TPN) + tid/TPN;
  if (TPN == 64) node = __builtin_amdgcn_readfirstlane(node);
  const int c8   = (tid & (TPN-1))*8;
  const int deg  = min(cnt[node], DEGCAP);
  const int* __restrict__ arow = adj + (size_t)node*DEGCAP;
  const __bf16* p = f + c8;
  float a[8];
  {
    bf16x8 sv = *(const bf16x8*)(p + (size_t)node*C);
#pragma unroll
    for (int t=0;t<8;t++) a[t] = (float)sv[t];
  }
  int j = 0;
  for (; j+8<=deg; j+=8){
    int sIdx[8];
#pragma unroll
    for (int u=0;u<8;u++) sIdx[u] = arow[j+u];
    bf16x8 v[8];
#pragma unroll
    for (int u=0;u<8;u++) v[u] = *(const bf16x8*)(p + (size_t)sIdx[u]*C);
#pragma unroll
    for (int u=0;u<8;u++)
#pragma unroll
      for (int t=0;t<8;t++) a[t] += (float)v[u][t];
  }
  for (; j+2<=deg; j+=2){
    int s0=arow[j], s1=arow[j+1];
    bf16x8 v0=*(const bf16x8*)(p+(size_t)s0*C), v1=*(const bf16x8*)(p+(size_t)s1*C);
#pragma unroll
    for (int t=0;t<8;t++) a[t] += (float)v0[t] + (float)v1[t];
  }
  if (j < deg){
    int s=arow[j];
    bf16x8 v=*(const bf16x8*)(p+(size_t)s*C);
#pragma unroll
    for (int t=0;t<8;t++) a[t] += (float)v[t];
  }
  bf16x8 o;
#pragma unroll
  for (int t=0;t<8;t++) o[t] = (__bf16)a[t];
  *(bf16x8*)(z + (size_t)node*C + c8) = o;
}

// ---------------- 128x128-tile 4-wave GEMM, counted-vmcnt dbuf ----------------
// NXT==0: plain (GSWAP mapping). NXT>0: grid is (NXT h-tiles, 256 n-tiles) and an
// XCD-chunked bijective swizzle maps all h-blocks of one n-tile onto one XCD
// (A-panel fetched once into that XCD's L2).  T = NXT*256, T%8==0 -> bijective.
template<int K, int GSWAP, int NXT>
__global__ __launch_bounds__(256, 2)
void mfma_gemm(const __bf16* __restrict__ A, const __bf16* __restrict__ B,
               const float* __restrict__ bias,
               __bf16* __restrict__ outr, int ostride,
               float* __restrict__ outT, int cbase, int relu)
{
  constexpr int NK = K/32;
  __shared__ __align__(16) char smem[32768];

  const int tid = threadIdx.x;
  const int l   = tid & 63;
  const int w   = tid >> 6;
  const int wm  = w >> 1, wn = w & 1;

  int n0, h0;
  if (NXT > 0){
    constexpr int T   = NXT*256;
    constexpr int LOG = (NXT==8) ? 3 : 2;
    int p  = blockIdx.y*NXT + blockIdx.x;
    int Lg = (p & 7)*(T >> 3) + (p >> 3);
    h0 = (Lg & (NXT-1)) * 128;
    n0 = (Lg >> LOG) * 128;
  } else {
    n0 = (GSWAP ? blockIdx.y : blockIdx.x) * 128;
    h0 = (GSWAP ? blockIdx.x : blockIdx.y) * 128;
  }

  f32x4 acc[4][4];
#pragma unroll
  for (int m=0;m<4;m++)
#pragma unroll
    for (int n=0;n<4;n++) acc[m][n] = (f32x4){0.f,0.f,0.f,0.f};

  const __bf16* gsrc = (w<2) ? A : B;
  const int soff = (w<2) ? 0 : 8192;
  const int rbase = (w<2) ? n0 : h0;
  const int ci0 = (w & 1) * 4;
  const int cd = (l&3) ^ ((l>>3)&3);
  const __bf16* g0 = gsrc + (size_t)(rbase + (l>>2))*K + cd*8;

  const int r16 = l & 15, q = l >> 4;
  const int fsw = ((q ^ ((r16>>1)&3)) << 4);

  auto STAGE = [&](int ks, int bb){
    char* d = smem + bb*16384 + soff;
    const __bf16* gk = g0 + ks*32;
#pragma unroll
    for (int i=0;i<4;i++){
      __builtin_amdgcn_global_load_lds(
        (const __attribute__((address_space(1))) void*)(gk + (size_t)(ci0+i)*16*K),
        (__attribute__((address_space(3))) void*)(d + (ci0+i)*1024), 16, 0, 0);
    }
  };

  STAGE(0, 0);
  STAGE(1, 1);

  for (int ks=0; ks<NK; ks++){
    const int bb = ks & 1;
    if (ks < NK-1) asm volatile("s_waitcnt vmcnt(4)" ::: "memory");
    else           asm volatile("s_waitcnt vmcnt(0)" ::: "memory");
    asm volatile("s_barrier" ::: "memory");

    const char* base = smem + bb*16384;
    bf16x8 fa[4], fb[4];
#pragma unroll
    for (int m=0;m<4;m++)
      fa[m] = *(const bf16x8*)(base + (wm*64 + m*16 + r16)*64 + fsw);
#pragma unroll
    for (int n=0;n<4;n++)
      fb[n] = *(const bf16x8*)(base + 8192 + (wn*64 + n*16 + r16)*64 + fsw);
    asm volatile("s_waitcnt lgkmcnt(0)" ::: "memory");
    __builtin_amdgcn_sched_barrier(0);

    __builtin_amdgcn_s_setprio(1);
#pragma unroll
    for (int m=0;m<4;m++)
#pragma unroll
      for (int n=0;n<4;n++)
        acc[m][n] = __builtin_amdgcn_mfma_f32_16x16x32_bf16(fa[m], fb[n], acc[m][n], 0,0,0);
    __builtin_amdgcn_s_setprio(0);

    asm volatile("s_barrier" ::: "memory");
    if (ks+2 < NK) STAGE(ks+2, bb);
  }

  __syncthreads();
  float* scratch = (float*)(void*)smem + w*1088;

  float bv[4];
#pragma unroll
  for (int n=0;n<4;n++) bv[n] = bias[h0 + wn*64 + n*16 + r16];

#pragma unroll
  for (int m=0;m<4;m++){
#pragma unroll
    for (int n=0;n<4;n++)
#pragma unroll
      for (int r=0;r<4;r++){
        float v = acc[m][n][r] + bv[n];
        if (relu) v = fmaxf(v, 0.f);
        scratch[(q*4+r)*68 + n*16 + r16] = v;
      }
    if (outr){
      const int row = l>>2, ch = (l&3)*16;
      bf16x8 H0,H1;
#pragma unroll
      for (int t=0;t<16;t++){
        float xv = scratch[row*68 + ch + t];
        if (t<8) H0[t]=(__bf16)xv; else H1[t-8]=(__bf16)xv;
      }
      size_t o = (size_t)(n0 + wm*64 + m*16 + row)*ostride + h0 + wn*64 + ch;
      *(bf16x8*)(outr+o)   = H0;
      *(bf16x8*)(outr+o+8) = H1;
    }
    if (outT){
      const int b = n0 >> 12, nl = n0 & 4095;
      const int rr0 = (l&3)*4;
#pragma unroll
      for (int j=0;j<4;j++){
        const int c = (l>>2) + 16*j;
        f32x4 v;
#pragma unroll
        for (int i=0;i<4;i++) v[i] = scratch[(rr0+i)*68 + c];
        size_t o = ((size_t)b*1408 + cbase + h0 + wn*64 + c)*NN + nl + wm*64 + m*16 + rr0;
        *(f32x4*)(outT + o) = v;
      }
    }
  }
}

extern "C" void kernel_launch(void* const* d_in, const int* in_sizes, int n_in,
                              void* d_out, int out_size, void* d_ws, size_t ws_size,
                              hipStream_t stream)
{
  const float* x     = (const float*)d_in[0];
  const float* emb   = (const float*)d_in[1];
  const int*   ei    = (const int*)d_in[2];
  const int*   eflag = (const int*)d_in[3];
  const float* g_w   = (const float*)d_in[4];
  const float* g_b   = (const float*)d_in[5];
  const float* c_w   = (const float*)d_in[6];
  const float* c_b   = (const float*)d_in[7];
  const float* m1w1  = (const float*)d_in[8];
  const float* m1b1  = (const float*)d_in[9];
  const float* m1w2  = (const float*)d_in[10];
  const float* m1b2  = (const float*)d_in[11];
  const float* m2w1  = (const float*)d_in[12];
  const float* m2b1  = (const float*)d_in[13];
  const float* m2w2  = (const float*)d_in[14];
  const float* m2b2  = (const float*)d_in[15];
  const float* m3w1  = (const float*)d_in[16];
  const float* m3b1  = (const float*)d_in[17];
  const float* m3w2  = (const float*)d_in[18];
  const float* m3b2  = (const float*)d_in[19];
  const float* fc_w  = (const float*)d_in[20];
  const float* fc_b  = (const float*)d_in[21];
  float* out = (float*)d_out;
  char*  ws  = (char*)d_ws;

  // ---- workspace layout (audited, disjoint) ----
  __bf16* F0 = (__bf16*)(ws + 0);            // [  0,   4 MB)  [BN][64]
  __bf16* Z1 = (__bf16*)(ws + 4194304);      // [  4,   8 MB)
  __bf16* H1 = (__bf16*)(ws + 8388608);      // [  8,  16 MB)  [BN][128]
  __bf16* F1 = (__bf16*)(ws + 16777216);     // [ 16,  24 MB)
  __bf16* Z2 = (__bf16*)(ws + 25165824);     // [ 24,  32 MB)
  __bf16* H2 = (__bf16*)(ws + 33554432);     // [ 32,  40 MB)
  __bf16* FF = (__bf16*)(ws + 41943040);     // [ 40,  72 MB)  [BN][512]
  __bf16* Z3 = (__bf16*)(ws + 75497472);     // [ 72, 104 MB)
  __bf16* H3 = (__bf16*)(ws + 109051904);    // [104, 136 MB)  ends 142606336
  // Weights (single bf16, transposed [N][K]) — at 144 MB
  char* wb = ws + 150994944;
  __bf16* W11=(__bf16*)(wb+0);
  __bf16* W12=(__bf16*)(wb+16384);
  __bf16* W21=(__bf16*)(wb+49152);
  __bf16* W22=(__bf16*)(wb+81920);
  __bf16* W31=(__bf16*)(wb+147456);
  __bf16* W32=(__bf16*)(wb+671744);          // ends wb+1720320
  // adjacency
  int* adj = (int*)(ws + 153092096);         // 8 MB [BN][64]
  int* cnt = (int*)(ws + 161480704);         // 128 KB

  const int* srcp = ei;
  const int* tgtp = ei + EDGES;

  hipMemsetAsync(cnt, 0, BN_*4, stream);
  prep_kernel<<<7456, 256, 0, stream>>>(srcp, tgtp, cnt, adj,
      x, emb, eflag, g_w, g_b, c_w, c_b, fc_w, fc_b, F0, FF,
      m1w1, m1w2, m2w1, m2w2, m3w1, m3w2, W11, W12, W21, W22, W31, W32);

  // ---- GIN layer 1: 64 -> 128 -> 128 ----
  gather_k<64><<<BN_/32, 256, 0, stream>>>(F0, cnt, adj, Z1);
  mfma_gemm<64,0,0><<<dim3(BN_/128, 1), 256, 0, stream>>>(
      Z1, W11, m1b1, H1, 128, nullptr, 0, 1);
  mfma_gemm<128,0,0><<<dim3(BN_/128, 1), 256, 0, stream>>>(
      H1, W12, m1b2, F1, 128, out, 0, 1);

  // ---- GIN layer 2: 128 -> 128 -> 256 ----
  gather_k<128><<<BN_/16, 256, 0, stream>>>(F1, cnt, adj, Z2);
  mfma_gemm<128,0,0><<<dim3(BN_/128, 1), 256, 0, stream>>>(
      Z2, W21, m2b1, H2, 128, nullptr, 0, 1);
  mfma_gemm<128,0,0><<<dim3(BN_/128, 2), 256, 0, stream>>>(
      H2, W22, m2b2, FF, 512, out, 128, 1);

  // ---- GIN layer 3: 512 -> 512 -> 1024 (XCD-chunked swizzle) ----
  gather_k<512><<<BN_/4, 256, 0, stream>>>(FF, cnt, adj, Z3);
  mfma_gemm<512,1,4><<<dim3(4, BN_/128), 256, 0, stream>>>(
      Z3, W31, m3b1, H3, 512, nullptr, 0, 1);
  mfma_gemm<512,1,8><<<dim3(8, BN_/128), 256, 0, stream>>>(
      H3, W32, m3b2, nullptr, 0, out, 384, 0);
}